// Round 12
// baseline (1408.460 us; speedup 1.0000x reference)
//
#include <hip/hip_runtime.h>

// LSTM_26912265077001: 2-layer LSTM (H=51, IN=1), T=512, B=1024, fp32.
//
// V12 (resubmit; round-11 bench failed on container infra, kernel audit
// clean: uniform barriers, in-bounds, legal 1-wave/SIMD launch).
//
// V12: "fat wave" — 4 waves/block (1 per SIMD), each wave does BOTH
// layers for its j-group. Rationale (V11 post-mortem): issue accounting
// across V1..V11 shows every kernel ran at ~600MHz effective clock and
// V9/V11 are SIMD-issue-bound (VALU 73% + MFMA 24% ~= 97%). Wall =
// 512 x per-SIMD-per-iter issue. V9: 2 waves/SIMD x ~625cy = 1250cy.
// V12: 1 wave/SIMD doing L1+L2 = ~960cy (-23%). Also: 64-block configs
// measured FASTER than 256-block (V11 +12% regression = DVFS), keep 64.
//  - NB=16 batches/block (full MFMA M-dim, all E-lanes real), 64 blocks.
//  - 48 B-fragments/thread = 192 VGPR persistent -> amdgpu_waves_per_eu(1,1)
//    (512-reg cap at 1 wave/EU) + opaque ldfrag (V9 infra).
//  - Same parity pipeline as V9: L1(it) + L2(it-1) per iteration,
//    1 barrier/iter, y[it-2] direct global store (V9 fastest; V10's
//    ybuf+chain-splits REGRESSED -> reverted).
// Numerics identical to V9 (same 3-term order, same packing).

#define Hs    51
#define Ts    512
#define Bs    1024
#define NB    16
#define NT    256
#define SA    136        // A row stride in ushorts (272B, 16B-aligned)
#define XCOL  51
#define H2COL 64

typedef __attribute__((ext_vector_type(8))) short bf16x8;
typedef __attribute__((ext_vector_type(4))) float f32x4;
typedef __attribute__((ext_vector_type(4))) int   i32x4;
typedef unsigned short u16;

__device__ __forceinline__ float sig_(float x)  { return 1.0f / (1.0f + __expf(-x)); }
__device__ __forceinline__ float tanh_(float x) { float e = __expf(2.0f * x); return 1.0f - 2.0f / (e + 1.0f); }
__device__ __forceinline__ u16 bfh_(float x) {   // fp32 -> bf16 (RNE)
    unsigned u = __float_as_uint(x);
    return (u16)((u + 0x7FFFu + ((u >> 16) & 1u)) >> 16);
}
__device__ __forceinline__ float bff_(u16 h) { return __uint_as_float(((unsigned)h) << 16); }

struct FragHL { bf16x8 h; bf16x8 l; };

// B1 fragment: row of [W_hh1 | W_ih1] at K-step ks, chunk ch.
__device__ __forceinline__ FragHL mkB1(const float* __restrict__ Whh1,
                                       const float* __restrict__ Wih1,
                                       int row, bool rv, int ks, int ch) {
    bf16x8 h = {0,0,0,0,0,0,0,0}, l = {0,0,0,0,0,0,0,0};
    #pragma unroll
    for (int j = 0; j < 8; ++j) {
        const int k = ks * 32 + ch * 8 + j;
        float v = 0.f;
        if (rv) {
            if (k < Hs)         v = Whh1[row * Hs + k];
            else if (k == XCOL) v = Wih1[row];
        }
        u16 hh = bfh_(v);
        h[j] = (short)hh;
        l[j] = (short)bfh_(v - bff_(hh));
    }
    FragHL r; r.h = h; r.l = l; return r;
}

// B2 fragment: row of [W_ih2 | 0 | W_hh2 | 0] at K-step ks, chunk ch.
__device__ __forceinline__ FragHL mkB2(const float* __restrict__ Wih2,
                                       const float* __restrict__ Whh2,
                                       int row, bool rv, int ks, int ch) {
    bf16x8 h = {0,0,0,0,0,0,0,0}, l = {0,0,0,0,0,0,0,0};
    #pragma unroll
    for (int j = 0; j < 8; ++j) {
        const int k = ks * 32 + ch * 8 + j;
        float v = 0.f;
        if (rv) {
            if (k < Hs)                              v = Wih2[row * Hs + k];
            else if (k >= H2COL && k < H2COL + Hs)   v = Whh2[row * Hs + (k - H2COL)];
        }
        u16 hh = bfh_(v);
        h[j] = (short)hh;
        l[j] = (short)bfh_(v - bff_(hh));
    }
    FragHL r; r.h = h; r.l = l; return r;
}

// ---- packed weights: per tid 48 frag slots (16 L1 + 32 L2) + 8 biases ----
__device__ __align__(16) u16   g_pack[NT * 48 * 8];   // 192 KB
__device__ __align__(16) float g_bias[NT * 8];

__global__ __launch_bounds__(NT) void prep_kernel(
    const float* __restrict__ W_ih1, const float* __restrict__ W_hh1,
    const float* __restrict__ b_ih1, const float* __restrict__ b_hh1,
    const float* __restrict__ W_ih2, const float* __restrict__ W_hh2,
    const float* __restrict__ b_ih2, const float* __restrict__ b_hh2)
{
    const int tid  = threadIdx.x;
    const int lane = tid & 63;
    const int jg   = tid >> 6;
    const int m    = lane & 15;
    const int ch   = lane >> 4;
    const int jrow = jg * 16 + m;
    const bool rv  = jrow < Hs;
    u16* base = &g_pack[tid * 384];

    for (int g = 0; g < 4; ++g) {
        const int row = g * Hs + jrow;
        g_bias[tid * 8 + g]     = rv ? (b_ih1[row] + b_hh1[row]) : 0.f;
        g_bias[tid * 8 + 4 + g] = rv ? (b_ih2[row] + b_hh2[row]) : 0.f;
        for (int s = 0; s < 2; ++s) {                 // L1: slots g*4+s*2+hl
            FragHL f = mkB1(W_hh1, W_ih1, row, rv, s, ch);
            *(bf16x8*)(base + (g * 4 + s * 2 + 0) * 8) = f.h;
            *(bf16x8*)(base + (g * 4 + s * 2 + 1) * 8) = f.l;
        }
        for (int s = 0; s < 4; ++s) {                 // L2: slots 16+g*8+s*2+hl
            FragHL f = mkB2(W_ih2, W_hh2, row, rv, s, ch);
            *(bf16x8*)(base + (16 + g * 8 + s * 2 + 0) * 8) = f.h;
            *(bf16x8*)(base + (16 + g * 8 + s * 2 + 1) * 8) = f.l;
        }
    }
}

// opaque fragment load: value cannot be rematerialized by the compiler
__device__ __forceinline__ bf16x8 ldfrag(const u16* p) {
    i32x4 v = *(const i32x4*)p;
    asm volatile("" : "+v"(v));
    union { i32x4 i; bf16x8 b; } u;
    u.i = v;
    return u.b;
}

#define MFMA_(A, B, C) __builtin_amdgcn_mfma_f32_16x16x32_bf16(A, B, C, 0, 0, 0)
// 3-term split-product accumulate, same term order as V5..V9
#define MF(ACC, AFH, AFL, BH, BL)                                              \
    ACC = MFMA_(AFH, BL, ACC);                                                 \
    ACC = MFMA_(AFL, BH, ACC);                                                 \
    ACC = MFMA_(AFH, BH, ACC);

__global__ __launch_bounds__(NT)
__attribute__((amdgpu_waves_per_eu(1, 1)))
void lstm2_kernel(
    const float* __restrict__ x,      // (T, B, 1)
    const float* __restrict__ W_lin,  // (1, 51)
    const float* __restrict__ b_lin,  // (1,)
    float* __restrict__ out)          // (B, T)
{
    __shared__ __align__(16) u16      Ah[2][NB * SA];
    __shared__ __align__(16) u16      Al[2][NB * SA];
    __shared__ __align__(16) unsigned xs32[Ts][NB];    // packed (hi,lo) x
    __shared__ __align__(16) float    h2f[2][NB][68];
    __shared__ __align__(16) float    wlin_s[64];
    __shared__ float blin_sh;

    const int tid  = threadIdx.x;
    const int lane = tid & 63;
    const int jg   = tid >> 6;         // wave 0..3 = j-group
    const int m    = lane & 15;
    const int ch   = lane >> 4;
    const int bg0  = blockIdx.x * NB;
    const int  jrow = jg * 16 + m;     // unit index (valid < 51)
    const bool rv   = jrow < Hs;

    // ---- one-time init: zero / preload (NO staging writes yet) ----
    for (int i = tid; i < Ts * NB; i += NT) {
        int t = i >> 4, b = i & 15;
        float xv = x[t * Bs + bg0 + b];
        u16 hh = bfh_(xv);
        u16 hl = bfh_(xv - bff_(hh));
        xs32[t][b] = (unsigned)hh | ((unsigned)hl << 16);
    }
    for (int i = tid; i < 2 * NB * SA; i += NT) {
        ((u16*)Ah)[i] = 0;
        ((u16*)Al)[i] = 0;
    }
    for (int i = tid; i < 2 * NB * 68; i += NT) ((float*)h2f)[i] = 0.f;
    if (tid < 64) wlin_s[tid] = (tid < Hs) ? W_lin[tid] : 0.f;
    if (tid == 0) blin_sh = b_lin[0];
    __syncthreads();                   // zero-fill visible first (V7 race fix)

    if (tid < NB) {                    // x[0] into parity 1 (read at it=0)
        unsigned v = xs32[0][tid];
        Ah[1][tid * SA + XCOL] = (u16)v;
        Al[1][tid * SA + XCOL] = (u16)(v >> 16);
    }

    // ---- biases: opaque register loads ----
    f32x4 bb1 = *(const f32x4*)&g_bias[tid * 8];
    f32x4 bb2 = *(const f32x4*)&g_bias[tid * 8 + 4];
    asm volatile("" : "+v"(bb1));
    asm volatile("" : "+v"(bb2));
    const float b1I = bb1.x, b1F = bb1.y, b1G = bb1.z, b1O = bb1.w;
    const float b2I = bb2.x, b2F = bb2.y, b2G = bb2.z, b2O = bb2.w;

    const u16* pk = &g_pack[tid * 384];

    // ---- 48 opaque weight fragments (persistent registers) ----
    // L1: slots g*4 + s*2 + hl
    bf16x8 bI0h = ldfrag(pk + (0*4+0)*8), bI0l = ldfrag(pk + (0*4+1)*8);
    bf16x8 bI1h = ldfrag(pk + (0*4+2)*8), bI1l = ldfrag(pk + (0*4+3)*8);
    bf16x8 bF0h = ldfrag(pk + (1*4+0)*8), bF0l = ldfrag(pk + (1*4+1)*8);
    bf16x8 bF1h = ldfrag(pk + (1*4+2)*8), bF1l = ldfrag(pk + (1*4+3)*8);
    bf16x8 bG0h = ldfrag(pk + (2*4+0)*8), bG0l = ldfrag(pk + (2*4+1)*8);
    bf16x8 bG1h = ldfrag(pk + (2*4+2)*8), bG1l = ldfrag(pk + (2*4+3)*8);
    bf16x8 bO0h = ldfrag(pk + (3*4+0)*8), bO0l = ldfrag(pk + (3*4+1)*8);
    bf16x8 bO1h = ldfrag(pk + (3*4+2)*8), bO1l = ldfrag(pk + (3*4+3)*8);
    // L2: slots 16 + g*8 + s*2 + hl
    bf16x8 cI0h = ldfrag(pk + (16+0*8+0)*8), cI0l = ldfrag(pk + (16+0*8+1)*8);
    bf16x8 cI1h = ldfrag(pk + (16+0*8+2)*8), cI1l = ldfrag(pk + (16+0*8+3)*8);
    bf16x8 cI2h = ldfrag(pk + (16+0*8+4)*8), cI2l = ldfrag(pk + (16+0*8+5)*8);
    bf16x8 cI3h = ldfrag(pk + (16+0*8+6)*8), cI3l = ldfrag(pk + (16+0*8+7)*8);
    bf16x8 cF0h = ldfrag(pk + (16+1*8+0)*8), cF0l = ldfrag(pk + (16+1*8+1)*8);
    bf16x8 cF1h = ldfrag(pk + (16+1*8+2)*8), cF1l = ldfrag(pk + (16+1*8+3)*8);
    bf16x8 cF2h = ldfrag(pk + (16+1*8+4)*8), cF2l = ldfrag(pk + (16+1*8+5)*8);
    bf16x8 cF3h = ldfrag(pk + (16+1*8+6)*8), cF3l = ldfrag(pk + (16+1*8+7)*8);
    bf16x8 cG0h = ldfrag(pk + (16+2*8+0)*8), cG0l = ldfrag(pk + (16+2*8+1)*8);
    bf16x8 cG1h = ldfrag(pk + (16+2*8+2)*8), cG1l = ldfrag(pk + (16+2*8+3)*8);
    bf16x8 cG2h = ldfrag(pk + (16+2*8+4)*8), cG2l = ldfrag(pk + (16+2*8+5)*8);
    bf16x8 cG3h = ldfrag(pk + (16+2*8+6)*8), cG3l = ldfrag(pk + (16+2*8+7)*8);
    bf16x8 cO0h = ldfrag(pk + (16+3*8+0)*8), cO0l = ldfrag(pk + (16+3*8+1)*8);
    bf16x8 cO1h = ldfrag(pk + (16+3*8+2)*8), cO1l = ldfrag(pk + (16+3*8+3)*8);
    bf16x8 cO2h = ldfrag(pk + (16+3*8+4)*8), cO2l = ldfrag(pk + (16+3*8+5)*8);
    bf16x8 cO3h = ldfrag(pk + (16+3*8+6)*8), cO3l = ldfrag(pk + (16+3*8+7)*8);

    float c10 = 0.f, c11 = 0.f, c12 = 0.f, c13 = 0.f;   // L1 cell states
    float c20 = 0.f, c21 = 0.f, c22 = 0.f, c23 = 0.f;   // L2 cell states
    __syncthreads();                   // staging + wlin visible

    const float wl0 = wlin_s[m],      wl1 = wlin_s[m + 16];
    const float wl2 = wlin_s[m + 32], wl3 = wlin_s[m + 48];
    const float blin_r = blin_sh;

    for (int it = 0; it <= Ts + 1; ++it) {
        const int pR = (it - 1) & 1;
        const int pW = it & 1;

        // ================ layer 1, timestep it ================
        if (it < Ts) {
            const u16* ph = &Ah[pR][m * SA + ch * 8];
            const u16* pl = &Al[pR][m * SA + ch * 8];
            bf16x8 A0h = *(const bf16x8*)(ph);
            bf16x8 A0l = *(const bf16x8*)(pl);
            bf16x8 A1h = *(const bf16x8*)(ph + 32);
            bf16x8 A1l = *(const bf16x8*)(pl + 32);
            f32x4 aI = {b1I, b1I, b1I, b1I};
            f32x4 aF = {b1F, b1F, b1F, b1F};
            f32x4 aG = {b1G, b1G, b1G, b1G};
            f32x4 aO = {b1O, b1O, b1O, b1O};
            MF(aI, A0h, A0l, bI0h, bI0l)  MF(aF, A0h, A0l, bF0h, bF0l)
            MF(aG, A0h, A0l, bG0h, bG0l)  MF(aO, A0h, A0l, bO0h, bO0l)
            MF(aI, A1h, A1l, bI1h, bI1l)  MF(aF, A1h, A1l, bF1h, bF1l)
            MF(aG, A1h, A1l, bG1h, bG1l)  MF(aO, A1h, A1l, bO1h, bO1l)
            #define E1STEP(RR, CC)                                             \
            {                                                                  \
                float iv = sig_ (aI[RR]);                                      \
                float fv = sig_ (aF[RR]);                                      \
                float gv = tanh_(aG[RR]);                                      \
                float ov = sig_ (aO[RR]);                                      \
                CC = fmaf(fv, CC, iv * gv);                                    \
                float hv = ov * tanh_(CC);                                     \
                if (rv) {                                                      \
                    const int b = 4 * ch + RR;                                 \
                    u16 hh = bfh_(hv);                                         \
                    Ah[pW][b * SA + jrow] = hh;                                \
                    Al[pW][b * SA + jrow] = bfh_(hv - bff_(hh));               \
                }                                                              \
            }
            E1STEP(0, c10) E1STEP(1, c11) E1STEP(2, c12) E1STEP(3, c13)
            #undef E1STEP
        }

        // ================ layer 2, timestep it-1 ================
        if (it >= 1 && it <= Ts) {
            const u16* ph = &Ah[pR][m * SA + ch * 8];
            const u16* pl = &Al[pR][m * SA + ch * 8];
            bf16x8 A0h = *(const bf16x8*)(ph);
            bf16x8 A0l = *(const bf16x8*)(pl);
            bf16x8 A1h = *(const bf16x8*)(ph + 32);
            bf16x8 A1l = *(const bf16x8*)(pl + 32);
            bf16x8 A2h = *(const bf16x8*)(ph + 64);
            bf16x8 A2l = *(const bf16x8*)(pl + 64);
            bf16x8 A3h = *(const bf16x8*)(ph + 96);
            bf16x8 A3l = *(const bf16x8*)(pl + 96);
            f32x4 aI = {b2I, b2I, b2I, b2I};
            f32x4 aF = {b2F, b2F, b2F, b2F};
            f32x4 aG = {b2G, b2G, b2G, b2G};
            f32x4 aO = {b2O, b2O, b2O, b2O};
            MF(aI, A0h, A0l, cI0h, cI0l)  MF(aF, A0h, A0l, cF0h, cF0l)
            MF(aG, A0h, A0l, cG0h, cG0l)  MF(aO, A0h, A0l, cO0h, cO0l)
            MF(aI, A1h, A1l, cI1h, cI1l)  MF(aF, A1h, A1l, cF1h, cF1l)
            MF(aG, A1h, A1l, cG1h, cG1l)  MF(aO, A1h, A1l, cO1h, cO1l)
            MF(aI, A2h, A2l, cI2h, cI2l)  MF(aF, A2h, A2l, cF2h, cF2l)
            MF(aG, A2h, A2l, cG2h, cG2l)  MF(aO, A2h, A2l, cO2h, cO2l)
            MF(aI, A3h, A3l, cI3h, cI3l)  MF(aF, A3h, A3l, cF3h, cF3l)
            MF(aG, A3h, A3l, cG3h, cG3l)  MF(aO, A3h, A3l, cO3h, cO3l)
            const int pE = (it - 1) & 1;     // h2f parity for h2[it-1]
            #define E2STEP(RR, CC)                                             \
            {                                                                  \
                float iv = sig_ (aI[RR]);                                      \
                float fv = sig_ (aF[RR]);                                      \
                float gv = tanh_(aG[RR]);                                      \
                float ov = sig_ (aO[RR]);                                      \
                CC = fmaf(fv, CC, iv * gv);                                    \
                float hv = ov * tanh_(CC);                                     \
                if (rv) {                                                      \
                    const int b = 4 * ch + RR;                                 \
                    u16 hh = bfh_(hv);                                         \
                    Ah[pW][b * SA + H2COL + jrow] = hh;                        \
                    Al[pW][b * SA + H2COL + jrow] = bfh_(hv - bff_(hh));       \
                    h2f[pE][b][jrow] = hv;                                     \
                }                                                              \
            }
            E2STEP(0, c20) E2STEP(1, c21) E2STEP(2, c22) E2STEP(3, c23)
            #undef E2STEP
        }

        // x[it+1] staging into parity pW (wave 0, 16 lanes; pre-split)
        if (jg == 0 && lane < NB && (it + 1) < Ts) {
            unsigned v = xs32[it + 1][lane];
            Ah[pW][lane * SA + XCOL] = (u16)v;
            Al[pW][lane * SA + XCOL] = (u16)(v >> 16);
        }
        // y[it-2] = W_lin . h2[it-2] + b ; wave jg handles batch 4*jg+ch
        if (it >= 2) {
            const float* hp = &h2f[it & 1][4 * jg + ch][0];
            float s = wl0 * hp[m] + wl1 * hp[m + 16]
                    + wl2 * hp[m + 32] + wl3 * hp[m + 48];
            s += __shfl_xor(s, 1);
            s += __shfl_xor(s, 2);
            s += __shfl_xor(s, 4);
            s += __shfl_xor(s, 8);
            if (m == 0) out[(bg0 + 4 * jg + ch) * Ts + (it - 2)] = s + blin_r;
        }
        __syncthreads();
    }
}

extern "C" void kernel_launch(void* const* d_in, const int* in_sizes, int n_in,
                              void* d_out, int out_size, void* d_ws, size_t ws_size,
                              hipStream_t stream) {
    const float* x     = (const float*)d_in[0];
    const float* W_ih1 = (const float*)d_in[1];
    const float* W_hh1 = (const float*)d_in[2];
    const float* b_ih1 = (const float*)d_in[3];
    const float* b_hh1 = (const float*)d_in[4];
    const float* W_ih2 = (const float*)d_in[5];
    const float* W_hh2 = (const float*)d_in[6];
    const float* b_ih2 = (const float*)d_in[7];
    const float* b_hh2 = (const float*)d_in[8];
    const float* W_lin = (const float*)d_in[9];
    const float* b_lin = (const float*)d_in[10];
    float* out = (float*)d_out;

    prep_kernel<<<1, NT, 0, stream>>>(W_ih1, W_hh1, b_ih1, b_hh1,
                                      W_ih2, W_hh2, b_ih2, b_hh2);
    lstm2_kernel<<<Bs / NB, NT, 0, stream>>>(x, W_lin, b_lin, out);
}